// Round 5
// baseline (254.827 us; speedup 1.0000x reference)
//
#include <hip/hip_runtime.h>

// DigitCaps dynamic routing, fully fused, register-resident priors.
// C=10, N=1152, DIN=8, DOUT=16, B=256, ITERS=3.
// One block = (c, batch-pair). Thread (rg=t>>2, oq=t&3) owns 9 rows x 1 o-quad
// x 2 batches of priors in VGPRs (FULLY unrolled -> static indexing -> no
// scratch; R4's '#pragma unroll 3' left runtime indices and spilled everything,
// WRITE_SIZE 184MB). XCD-chunked swizzle: each XCD owns 32 batches x all 10 c,
// c-slow -> resident set (<=4 W panels + 1.15MB x) fits 4MB L2.

#define C_    10
#define N_    1152
#define DIN_  8
#define DOUT_ 16
#define B_    256
#define TB    2
#define ITERS_ 3

#define THREADS 512
#define NWAVE   8
#define ROWS    9          // N_ / (THREADS/4)

static __device__ __forceinline__ float dot4(float4 a, float4 b) {
    return a.x*b.x + a.y*b.y + a.z*b.z + a.w*b.w;
}
static __device__ __forceinline__ void fma4(float4& a, float s, float4 v) {
    a.x += s*v.x; a.y += s*v.y; a.z += s*v.z; a.w += s*v.w;
}
static __device__ __forceinline__ void add4(float4& a, float4 v) {
    a.x += v.x; a.y += v.y; a.z += v.z; a.w += v.w;
}
static __device__ __forceinline__ float4 shfl_xor4(float4 v, int m) {
    return make_float4(__shfl_xor(v.x, m), __shfl_xor(v.y, m),
                       __shfl_xor(v.z, m), __shfl_xor(v.w, m));
}

__global__ __launch_bounds__(THREADS, 4)   // 4 waves/EU -> VGPR<=128, 2 blocks/CU
void caps_route_kernel(const float* __restrict__ x,   // [B, N, DIN]
                       const float* __restrict__ W,   // [C, N, DIN, DOUT]
                       float* __restrict__ out)       // [C, B, 1, DOUT]
{
    __shared__ float  redm[NWAVE][TB];        // wave maxes
    __shared__ float  reds[NWAVE][TB];        // wave denom partials
    __shared__ float4 sred[TB][NWAVE][4];     // wave s partials per oq

    const int t    = threadIdx.x;
    const int oq   = t & 3;
    const int rg   = t >> 2;       // 0..127
    const int wave = t >> 6;
    const int lane = t & 63;

    // XCD-chunked mapping: bid%8 -> XCD (round-robin dispatch heuristic).
    // Each XCD processes its 32-batch chunk across all c, c varying slowest.
    const int bid  = blockIdx.x;
    const int xcd  = bid & 7;
    const int pair = (bid >> 3) & 15;
    const int c    = bid >> 7;               // 0..9
    const int b0   = xcd * 32 + pair * 2;    // this XCD's private batch range

    const float4* Wc4 = (const float4*)W + (size_t)c * (N_ * 32) + oq;
    const float4* xA4 = (const float4*)x + (size_t)b0 * (N_ * 2);
    const float4* xB4 = xA4 + N_ * 2;

    // ---------------- priors -> registers (FULL unroll: static indices) ----
    float4 pA[ROWS], pB[ROWS];
    #pragma unroll
    for (int k = 0; k < ROWS; ++k) {
        const int n = rg + (k << 7);
        const float4* wr = Wc4 + n * 32;
        const float4 xa0 = xA4[n*2], xa1 = xA4[n*2 + 1];
        const float4 xb0 = xB4[n*2], xb1 = xB4[n*2 + 1];
        float4 a = make_float4(0.f,0.f,0.f,0.f);
        float4 b = make_float4(0.f,0.f,0.f,0.f);
        float4 w;
        w = wr[ 0]; fma4(a, xa0.x, w); fma4(b, xb0.x, w);
        w = wr[ 4]; fma4(a, xa0.y, w); fma4(b, xb0.y, w);
        w = wr[ 8]; fma4(a, xa0.z, w); fma4(b, xb0.z, w);
        w = wr[12]; fma4(a, xa0.w, w); fma4(b, xb0.w, w);
        w = wr[16]; fma4(a, xa1.x, w); fma4(b, xb1.x, w);
        w = wr[20]; fma4(a, xa1.y, w); fma4(b, xb1.y, w);
        w = wr[24]; fma4(a, xa1.z, w); fma4(b, xb1.z, w);
        w = wr[28]; fma4(a, xa1.w, w); fma4(b, xb1.w, w);
        pA[k] = a; pB[k] = b;
    }

    // ---------------- routing (all-register, shuffle reductions) ----------
    float lA[ROWS], lB[ROWS];
    #pragma unroll
    for (int k = 0; k < ROWS; ++k) { lA[k] = 0.f; lB[k] = 0.f; }
    float4 vA = make_float4(0.f,0.f,0.f,0.f);
    float4 vB = vA;

    for (int it = 0; it < ITERS_; ++it) {
        float4 sA = make_float4(0.f,0.f,0.f,0.f);
        float4 sB = sA;
        float invA, invB;

        if (it == 0) {
            #pragma unroll
            for (int k = 0; k < ROWS; ++k) { add4(sA, pA[k]); add4(sB, pB[k]); }
            invA = invB = 1.0f / (float)N_;
        } else {
            float mA = lA[0], mB = lB[0];
            #pragma unroll
            for (int k = 1; k < ROWS; ++k) { mA = fmaxf(mA, lA[k]); mB = fmaxf(mB, lB[k]); }
            #pragma unroll
            for (int off = 1; off < 64; off <<= 1) {
                mA = fmaxf(mA, __shfl_xor(mA, off));
                mB = fmaxf(mB, __shfl_xor(mB, off));
            }
            if (lane == 0) { redm[wave][0] = mA; redm[wave][1] = mB; }
            __syncthreads();
            mA = redm[0][0]; mB = redm[0][1];
            #pragma unroll
            for (int wv = 1; wv < NWAVE; ++wv) {
                mA = fmaxf(mA, redm[wv][0]); mB = fmaxf(mB, redm[wv][1]);
            }

            float dA = 0.f, dB = 0.f;
            #pragma unroll
            for (int k = 0; k < ROWS; ++k) {
                const float eA = __expf(lA[k] - mA); dA += eA; fma4(sA, eA, pA[k]);
                const float eB = __expf(lB[k] - mB); dB += eB; fma4(sB, eB, pB[k]);
            }
            #pragma unroll
            for (int off = 1; off < 64; off <<= 1) {
                dA += __shfl_xor(dA, off);
                dB += __shfl_xor(dB, off);
            }
            if (lane == 0) { reds[wave][0] = dA; reds[wave][1] = dB; }
            invA = invB = 0.f;
        }

        #pragma unroll
        for (int off = 4; off < 64; off <<= 1) {
            add4(sA, shfl_xor4(sA, off));
            add4(sB, shfl_xor4(sB, off));
        }
        if (lane < 4) { sred[0][wave][lane] = sA; sred[1][wave][lane] = sB; }
        __syncthreads();

        if (it != 0) {
            float dA = 0.f, dB = 0.f;
            #pragma unroll
            for (int wv = 0; wv < NWAVE; ++wv) { dA += reds[wv][0]; dB += reds[wv][1]; }
            invA = 4.0f / dA;   // x4 oq-replication in the butterfly sum
            invB = 4.0f / dB;
        }

        float4 s4A = make_float4(0.f,0.f,0.f,0.f);
        float4 s4B = s4A;
        #pragma unroll
        for (int wv = 0; wv < NWAVE; ++wv) { add4(s4A, sred[0][wv][oq]); add4(s4B, sred[1][wv][oq]); }
        s4A.x *= invA; s4A.y *= invA; s4A.z *= invA; s4A.w *= invA;
        s4B.x *= invB; s4B.y *= invB; s4B.z *= invB; s4B.w *= invB;

        float sqA = dot4(s4A, s4A);
        sqA += __shfl_xor(sqA, 1); sqA += __shfl_xor(sqA, 2);
        float sqB = dot4(s4B, s4B);
        sqB += __shfl_xor(sqB, 1); sqB += __shfl_xor(sqB, 2);
        const float scA = sqrtf(sqA) / (1.0f + sqA);
        const float scB = sqrtf(sqB) / (1.0f + sqB);
        vA = make_float4(scA*s4A.x, scA*s4A.y, scA*s4A.z, scA*s4A.w);
        vB = make_float4(scB*s4B.x, scB*s4B.y, scB*s4B.z, scB*s4B.w);

        if (it != ITERS_ - 1) {
            #pragma unroll
            for (int k = 0; k < ROWS; ++k) {
                float dAk = dot4(pA[k], vA);
                dAk += __shfl_xor(dAk, 1); dAk += __shfl_xor(dAk, 2);
                lA[k] += dAk;
                float dBk = dot4(pB[k], vB);
                dBk += __shfl_xor(dBk, 1); dBk += __shfl_xor(dBk, 2);
                lB[k] += dBk;
            }
        }
    }

    // ---------------- output ----------------
    if (t < 4) {   // t == oq here
        float4* o4 = (float4*)out;
        o4[((size_t)c * B_ + b0    ) * 4 + oq] = vA;
        o4[((size_t)c * B_ + b0 + 1) * 4 + oq] = vB;
    }
}

extern "C" void kernel_launch(void* const* d_in, const int* in_sizes, int n_in,
                              void* d_out, int out_size, void* d_ws, size_t ws_size,
                              hipStream_t stream) {
    const float* x = (const float*)d_in[0];   // [B, N, DIN]
    const float* W = (const float*)d_in[1];   // [C, N, DIN, DOUT]
    float* out = (float*)d_out;               // [C, B, 1, DOUT]
    (void)in_sizes; (void)n_in; (void)out_size; (void)d_ws; (void)ws_size;

    caps_route_kernel<<<dim3(C_ * (B_ / TB)), dim3(THREADS), 0, stream>>>(x, W, out);
}

// Round 6
// 244.859 us; speedup vs baseline: 1.0407x; 1.0407x over previous
//
#include <hip/hip_runtime.h>

// DigitCaps dynamic routing, fully fused, register-resident priors.
// C=10, N=1152, DIN=8, DOUT=16, B=256, ITERS=3.
// One block = (c, batch-pair). Thread (rg=t>>2, oq=t&3) owns 9 rows x 1 o-quad
// x 2 batches of priors as NAMED SCALARS (X-macros). R3-R5 lesson: float4
// arrays -> variable-index GEPs at SROA time -> alloca never promoted ->
// 200+MB scratch traffic, even with full #pragma unroll. Named scalars have
// no alloca to fail on. XCD-chunked swizzle keeps W panels L2-resident.

#define C_    10
#define N_    1152
#define DOUT_ 16
#define B_    256
#define TB    2
#define ITERS_ 3

#define THREADS 512
#define NWAVE   8

#define ROW_LIST(X) X(0) X(1) X(2) X(3) X(4) X(5) X(6) X(7) X(8)

static __device__ __forceinline__ float dot4(float4 a, float4 b) {
    return a.x*b.x + a.y*b.y + a.z*b.z + a.w*b.w;
}
static __device__ __forceinline__ void fma4(float4& a, float s, float4 v) {
    a.x += s*v.x; a.y += s*v.y; a.z += s*v.z; a.w += s*v.w;
}
static __device__ __forceinline__ void add4(float4& a, float4 v) {
    a.x += v.x; a.y += v.y; a.z += v.z; a.w += v.w;
}
static __device__ __forceinline__ float4 shfl_xor4(float4 v, int m) {
    return make_float4(__shfl_xor(v.x, m), __shfl_xor(v.y, m),
                       __shfl_xor(v.z, m), __shfl_xor(v.w, m));
}

__global__ __launch_bounds__(THREADS, 4)   // min 4 waves/EU -> VGPR budget 128
void caps_route_kernel(const float* __restrict__ x,   // [B, N, DIN]
                       const float* __restrict__ W,   // [C, N, DIN, DOUT]
                       float* __restrict__ out)       // [C, B, 1, DOUT]
{
    __shared__ float  redm[NWAVE][TB];        // wave maxes
    __shared__ float  reds[NWAVE][TB];        // wave denom partials
    __shared__ float4 sred[TB][NWAVE][4];     // wave s partials per oq

    const int t    = threadIdx.x;
    const int oq   = t & 3;
    const int rg   = t >> 2;       // 0..127
    const int wave = t >> 6;
    const int lane = t & 63;

    // XCD-chunked mapping: each XCD owns a 32-batch chunk across all c,
    // c varying slowest -> resident W panels + x chunk fit 4MB L2.
    const int bid  = blockIdx.x;
    const int xcd  = bid & 7;
    const int pair = (bid >> 3) & 15;
    const int c    = bid >> 7;               // 0..9
    const int b0   = xcd * 32 + pair * 2;

    const float4* Wc4 = (const float4*)W + (size_t)c * (N_ * 32) + oq;
    const float4* xA4 = (const float4*)x + (size_t)b0 * (N_ * 2);
    const float4* xB4 = xA4 + N_ * 2;

    // ---------------- priors -> named-scalar registers ----------------
#define DECL_P(r) float4 pA##r, pB##r;
    ROW_LIST(DECL_P)

#define PRIOR_ROW(r) { \
        const int n = rg + (r << 7); \
        const float4* wr = Wc4 + n * 32; \
        const float4 xa0 = xA4[n*2], xa1 = xA4[n*2 + 1]; \
        const float4 xb0 = xB4[n*2], xb1 = xB4[n*2 + 1]; \
        float4 a = make_float4(0.f,0.f,0.f,0.f); \
        float4 b = make_float4(0.f,0.f,0.f,0.f); \
        float4 w; \
        w = wr[ 0]; fma4(a, xa0.x, w); fma4(b, xb0.x, w); \
        w = wr[ 4]; fma4(a, xa0.y, w); fma4(b, xb0.y, w); \
        w = wr[ 8]; fma4(a, xa0.z, w); fma4(b, xb0.z, w); \
        w = wr[12]; fma4(a, xa0.w, w); fma4(b, xb0.w, w); \
        w = wr[16]; fma4(a, xa1.x, w); fma4(b, xb1.x, w); \
        w = wr[20]; fma4(a, xa1.y, w); fma4(b, xb1.y, w); \
        w = wr[24]; fma4(a, xa1.z, w); fma4(b, xb1.z, w); \
        w = wr[28]; fma4(a, xa1.w, w); fma4(b, xb1.w, w); \
        pA##r = a; pB##r = b; }
    ROW_LIST(PRIOR_ROW)

    // ---------------- routing (all-register, shuffle reductions) ----------
#define DECL_L(r) float lA##r = 0.f, lB##r = 0.f;
    ROW_LIST(DECL_L)

    float4 vA = make_float4(0.f,0.f,0.f,0.f);
    float4 vB = vA;

    for (int it = 0; it < ITERS_; ++it) {
        float4 sA = make_float4(0.f,0.f,0.f,0.f);
        float4 sB = sA;
        float invA, invB;

        if (it == 0) {
#define SUM0_ROW(r) add4(sA, pA##r); add4(sB, pB##r);
            ROW_LIST(SUM0_ROW)
            invA = invB = 1.0f / (float)N_;
        } else {
            float mA = -1e30f, mB = -1e30f;
#define MAX_ROW(r) mA = fmaxf(mA, lA##r); mB = fmaxf(mB, lB##r);
            ROW_LIST(MAX_ROW)
            #pragma unroll
            for (int off = 1; off < 64; off <<= 1) {
                mA = fmaxf(mA, __shfl_xor(mA, off));
                mB = fmaxf(mB, __shfl_xor(mB, off));
            }
            if (lane == 0) { redm[wave][0] = mA; redm[wave][1] = mB; }
            __syncthreads();
            mA = redm[0][0]; mB = redm[0][1];
            #pragma unroll
            for (int wv = 1; wv < NWAVE; ++wv) {
                mA = fmaxf(mA, redm[wv][0]); mB = fmaxf(mB, redm[wv][1]);
            }

            float dA = 0.f, dB = 0.f;
#define EXP_ROW(r) { \
            const float eA = __expf(lA##r - mA); dA += eA; fma4(sA, eA, pA##r); \
            const float eB = __expf(lB##r - mB); dB += eB; fma4(sB, eB, pB##r); }
            ROW_LIST(EXP_ROW)
            #pragma unroll
            for (int off = 1; off < 64; off <<= 1) {
                dA += __shfl_xor(dA, off);
                dB += __shfl_xor(dB, off);
            }
            if (lane == 0) { reds[wave][0] = dA; reds[wave][1] = dB; }
            invA = invB = 0.f;
        }

        #pragma unroll
        for (int off = 4; off < 64; off <<= 1) {
            add4(sA, shfl_xor4(sA, off));
            add4(sB, shfl_xor4(sB, off));
        }
        if (lane < 4) { sred[0][wave][lane] = sA; sred[1][wave][lane] = sB; }
        __syncthreads();

        if (it != 0) {
            float dA = 0.f, dB = 0.f;
            #pragma unroll
            for (int wv = 0; wv < NWAVE; ++wv) { dA += reds[wv][0]; dB += reds[wv][1]; }
            invA = 4.0f / dA;   // x4 oq-replication in the butterfly sum
            invB = 4.0f / dB;
        }

        float4 s4A = make_float4(0.f,0.f,0.f,0.f);
        float4 s4B = s4A;
        #pragma unroll
        for (int wv = 0; wv < NWAVE; ++wv) { add4(s4A, sred[0][wv][oq]); add4(s4B, sred[1][wv][oq]); }
        s4A.x *= invA; s4A.y *= invA; s4A.z *= invA; s4A.w *= invA;
        s4B.x *= invB; s4B.y *= invB; s4B.z *= invB; s4B.w *= invB;

        float sqA = dot4(s4A, s4A);
        sqA += __shfl_xor(sqA, 1); sqA += __shfl_xor(sqA, 2);
        float sqB = dot4(s4B, s4B);
        sqB += __shfl_xor(sqB, 1); sqB += __shfl_xor(sqB, 2);
        const float scA = sqrtf(sqA) / (1.0f + sqA);
        const float scB = sqrtf(sqB) / (1.0f + sqB);
        vA = make_float4(scA*s4A.x, scA*s4A.y, scA*s4A.z, scA*s4A.w);
        vB = make_float4(scB*s4B.x, scB*s4B.y, scB*s4B.z, scB*s4B.w);

        if (it != ITERS_ - 1) {
#define UPD_ROW(r) { \
            float dAk = dot4(pA##r, vA); \
            dAk += __shfl_xor(dAk, 1); dAk += __shfl_xor(dAk, 2); \
            lA##r += dAk; \
            float dBk = dot4(pB##r, vB); \
            dBk += __shfl_xor(dBk, 1); dBk += __shfl_xor(dBk, 2); \
            lB##r += dBk; }
            ROW_LIST(UPD_ROW)
        }
    }

    // ---------------- output ----------------
    if (t < 4) {   // t == oq here; threads 0..3 hold full v quads
        float4* o4 = (float4*)out;
        o4[((size_t)c * B_ + b0    ) * 4 + oq] = vA;
        o4[((size_t)c * B_ + b0 + 1) * 4 + oq] = vB;
    }
}

extern "C" void kernel_launch(void* const* d_in, const int* in_sizes, int n_in,
                              void* d_out, int out_size, void* d_ws, size_t ws_size,
                              hipStream_t stream) {
    const float* x = (const float*)d_in[0];   // [B, N, DIN]
    const float* W = (const float*)d_in[1];   // [C, N, DIN, DOUT]
    float* out = (float*)d_out;               // [C, B, 1, DOUT]
    (void)in_sizes; (void)n_in; (void)out_size; (void)d_ws; (void)ws_size;

    caps_route_kernel<<<dim3(C_ * (B_ / TB)), dim3(THREADS), 0, stream>>>(x, W, out);
}

// Round 7
// 140.740 us; speedup vs baseline: 1.8106x; 1.7398x over previous
//
#include <hip/hip_runtime.h>

// DigitCaps dynamic routing, fully fused, register-resident priors.
// C=10, N=1152, DIN=8, DOUT=16, B=256, ITERS=3.
// One block = (c, batch-pair). Thread (rg=t>>2, oq=t&3) owns 9 rows x 1 o-quad
// x 2 batches of priors as named scalars.
//
// R4-R6 lesson: __launch_bounds__(512, 4) made the backend budget for FULL
// occupancy (32 waves/CU -> 2048/32 = exactly 64 VGPRs) and force-spill ~60
// regs/thread -> 270MB of HBM scratch traffic. (512, 2) => 16 waves/CU =>
// 128-VGPR budget, which fits this kernel's ~124-reg peak. 2 blocks/CU is
// also the L2-residency sweet spot for the XCD-chunked W panels.

#define C_    10
#define N_    1152
#define DOUT_ 16
#define B_    256
#define TB    2
#define ITERS_ 3

#define THREADS 512
#define NWAVE   8

#define ROW_LIST(X) X(0) X(1) X(2) X(3) X(4) X(5) X(6) X(7) X(8)

static __device__ __forceinline__ float dot4(float4 a, float4 b) {
    return a.x*b.x + a.y*b.y + a.z*b.z + a.w*b.w;
}
static __device__ __forceinline__ void fma4(float4& a, float s, float4 v) {
    a.x += s*v.x; a.y += s*v.y; a.z += s*v.z; a.w += s*v.w;
}
static __device__ __forceinline__ void add4(float4& a, float4 v) {
    a.x += v.x; a.y += v.y; a.z += v.z; a.w += v.w;
}
static __device__ __forceinline__ float4 shfl_xor4(float4 v, int m) {
    return make_float4(__shfl_xor(v.x, m), __shfl_xor(v.y, m),
                       __shfl_xor(v.z, m), __shfl_xor(v.w, m));
}

__global__ __launch_bounds__(THREADS, 2)   // 2 blocks/CU -> 128-VGPR budget
void caps_route_kernel(const float* __restrict__ x,   // [B, N, DIN]
                       const float* __restrict__ W,   // [C, N, DIN, DOUT]
                       float* __restrict__ out)       // [C, B, 1, DOUT]
{
    __shared__ float  redm[NWAVE][TB];        // wave maxes
    __shared__ float  reds[NWAVE][TB];        // wave denom partials
    __shared__ float4 sred[TB][NWAVE][4];     // wave s partials per oq

    const int t    = threadIdx.x;
    const int oq   = t & 3;
    const int rg   = t >> 2;       // 0..127
    const int wave = t >> 6;
    const int lane = t & 63;

    // XCD-chunked mapping: each XCD owns a 32-batch chunk across all c,
    // c varying slowest -> resident W panels + x chunk fit 4MB L2.
    const int bid  = blockIdx.x;
    const int xcd  = bid & 7;
    const int pair = (bid >> 3) & 15;
    const int c    = bid >> 7;               // 0..9
    const int b0   = xcd * 32 + pair * 2;

    const float4* Wc4 = (const float4*)W + (size_t)c * (N_ * 32) + oq;
    const float4* xA4 = (const float4*)x + (size_t)b0 * (N_ * 2);
    const float4* xB4 = xA4 + N_ * 2;

    // ---------------- priors -> named-scalar registers ----------------
#define DECL_P(r) float4 pA##r, pB##r;
    ROW_LIST(DECL_P)

#define PRIOR_ROW(r) { \
        const int n = rg + (r << 7); \
        const float4* wr = Wc4 + n * 32; \
        const float4 xa0 = xA4[n*2], xa1 = xA4[n*2 + 1]; \
        const float4 xb0 = xB4[n*2], xb1 = xB4[n*2 + 1]; \
        float4 a = make_float4(0.f,0.f,0.f,0.f); \
        float4 b = make_float4(0.f,0.f,0.f,0.f); \
        float4 w; \
        w = wr[ 0]; fma4(a, xa0.x, w); fma4(b, xb0.x, w); \
        w = wr[ 4]; fma4(a, xa0.y, w); fma4(b, xb0.y, w); \
        w = wr[ 8]; fma4(a, xa0.z, w); fma4(b, xb0.z, w); \
        w = wr[12]; fma4(a, xa0.w, w); fma4(b, xb0.w, w); \
        w = wr[16]; fma4(a, xa1.x, w); fma4(b, xb1.x, w); \
        w = wr[20]; fma4(a, xa1.y, w); fma4(b, xb1.y, w); \
        w = wr[24]; fma4(a, xa1.z, w); fma4(b, xb1.z, w); \
        w = wr[28]; fma4(a, xa1.w, w); fma4(b, xb1.w, w); \
        pA##r = a; pB##r = b; }
    ROW_LIST(PRIOR_ROW)

    // ---------------- routing (all-register, shuffle reductions) ----------
#define DECL_L(r) float lA##r = 0.f, lB##r = 0.f;
    ROW_LIST(DECL_L)

    float4 vA = make_float4(0.f,0.f,0.f,0.f);
    float4 vB = vA;

    for (int it = 0; it < ITERS_; ++it) {
        float4 sA = make_float4(0.f,0.f,0.f,0.f);
        float4 sB = sA;
        float invA, invB;

        if (it == 0) {
#define SUM0_ROW(r) add4(sA, pA##r); add4(sB, pB##r);
            ROW_LIST(SUM0_ROW)
            invA = invB = 1.0f / (float)N_;
        } else {
            float mA = -1e30f, mB = -1e30f;
#define MAX_ROW(r) mA = fmaxf(mA, lA##r); mB = fmaxf(mB, lB##r);
            ROW_LIST(MAX_ROW)
            #pragma unroll
            for (int off = 1; off < 64; off <<= 1) {
                mA = fmaxf(mA, __shfl_xor(mA, off));
                mB = fmaxf(mB, __shfl_xor(mB, off));
            }
            if (lane == 0) { redm[wave][0] = mA; redm[wave][1] = mB; }
            __syncthreads();
            mA = redm[0][0]; mB = redm[0][1];
            #pragma unroll
            for (int wv = 1; wv < NWAVE; ++wv) {
                mA = fmaxf(mA, redm[wv][0]); mB = fmaxf(mB, redm[wv][1]);
            }

            float dA = 0.f, dB = 0.f;
#define EXP_ROW(r) { \
            const float eA = __expf(lA##r - mA); dA += eA; fma4(sA, eA, pA##r); \
            const float eB = __expf(lB##r - mB); dB += eB; fma4(sB, eB, pB##r); }
            ROW_LIST(EXP_ROW)
            #pragma unroll
            for (int off = 1; off < 64; off <<= 1) {
                dA += __shfl_xor(dA, off);
                dB += __shfl_xor(dB, off);
            }
            if (lane == 0) { reds[wave][0] = dA; reds[wave][1] = dB; }
            invA = invB = 0.f;
        }

        #pragma unroll
        for (int off = 4; off < 64; off <<= 1) {
            add4(sA, shfl_xor4(sA, off));
            add4(sB, shfl_xor4(sB, off));
        }
        if (lane < 4) { sred[0][wave][lane] = sA; sred[1][wave][lane] = sB; }
        __syncthreads();

        if (it != 0) {
            float dA = 0.f, dB = 0.f;
            #pragma unroll
            for (int wv = 0; wv < NWAVE; ++wv) { dA += reds[wv][0]; dB += reds[wv][1]; }
            invA = 4.0f / dA;   // x4 oq-replication in the butterfly sum
            invB = 4.0f / dB;
        }

        float4 s4A = make_float4(0.f,0.f,0.f,0.f);
        float4 s4B = s4A;
        #pragma unroll
        for (int wv = 0; wv < NWAVE; ++wv) { add4(s4A, sred[0][wv][oq]); add4(s4B, sred[1][wv][oq]); }
        s4A.x *= invA; s4A.y *= invA; s4A.z *= invA; s4A.w *= invA;
        s4B.x *= invB; s4B.y *= invB; s4B.z *= invB; s4B.w *= invB;

        float sqA = dot4(s4A, s4A);
        sqA += __shfl_xor(sqA, 1); sqA += __shfl_xor(sqA, 2);
        float sqB = dot4(s4B, s4B);
        sqB += __shfl_xor(sqB, 1); sqB += __shfl_xor(sqB, 2);
        const float scA = sqrtf(sqA) / (1.0f + sqA);
        const float scB = sqrtf(sqB) / (1.0f + sqB);
        vA = make_float4(scA*s4A.x, scA*s4A.y, scA*s4A.z, scA*s4A.w);
        vB = make_float4(scB*s4B.x, scB*s4B.y, scB*s4B.z, scB*s4B.w);

        if (it != ITERS_ - 1) {
#define UPD_ROW(r) { \
            float dAk = dot4(pA##r, vA); \
            dAk += __shfl_xor(dAk, 1); dAk += __shfl_xor(dAk, 2); \
            lA##r += dAk; \
            float dBk = dot4(pB##r, vB); \
            dBk += __shfl_xor(dBk, 1); dBk += __shfl_xor(dBk, 2); \
            lB##r += dBk; }
            ROW_LIST(UPD_ROW)
        }
    }

    // ---------------- output ----------------
    if (t < 4) {   // t == oq here; threads 0..3 hold full v quads
        float4* o4 = (float4*)out;
        o4[((size_t)c * B_ + b0    ) * 4 + oq] = vA;
        o4[((size_t)c * B_ + b0 + 1) * 4 + oq] = vB;
    }
}

extern "C" void kernel_launch(void* const* d_in, const int* in_sizes, int n_in,
                              void* d_out, int out_size, void* d_ws, size_t ws_size,
                              hipStream_t stream) {
    const float* x = (const float*)d_in[0];   // [B, N, DIN]
    const float* W = (const float*)d_in[1];   // [C, N, DIN, DOUT]
    float* out = (float*)d_out;               // [C, B, 1, DOUT]
    (void)in_sizes; (void)n_in; (void)out_size; (void)d_ws; (void)ws_size;

    caps_route_kernel<<<dim3(C_ * (B_ / TB)), dim3(THREADS), 0, stream>>>(x, W, out);
}